// Round 1
// baseline (961.797 us; speedup 1.0000x reference)
//
#include <hip/hip_runtime.h>
#include <hip/hip_bf16.h>
#include <cmath>
#include <cstdint>

// Problem constants
#define SEQ    2048
#define HID    3584
#define NH     28
#define NKV    4
#define HD     128
#define NTOT   4608          // 3584 q + 512 k + 512 v
#define KOFF   3584
#define VOFF   4096
#define QSCALE 0.08838834764831845f   // 1/sqrt(128)
#define LOG2E  1.4426950408889634f

typedef __attribute__((ext_vector_type(8))) short bf16x8;
typedef __attribute__((ext_vector_type(4))) float f32x4;

__device__ inline short f2bf(float f){
    union { float f; uint32_t u; } c; c.f = f;
    uint32_t u = c.u;
    uint32_t r = (u + 0x7fffu + ((u >> 16) & 1u)) >> 16;
    return (short)r;
}

// ---------------------------------------------------------------- convert
__global__ void cvt_f32_bf16(const float* __restrict__ src, short* __restrict__ dst, int n8){
    int i = blockIdx.x * blockDim.x + threadIdx.x;
    if (i >= n8) return;
    float4 a = ((const float4*)src)[2*i];
    float4 b = ((const float4*)src)[2*i+1];
    bf16x8 o;
    o[0]=f2bf(a.x); o[1]=f2bf(a.y); o[2]=f2bf(a.z); o[3]=f2bf(a.w);
    o[4]=f2bf(b.x); o[5]=f2bf(b.y); o[6]=f2bf(b.z); o[7]=f2bf(b.w);
    ((bf16x8*)dst)[i] = o;
}

// ---------------------------------------------------------------- QKV GEMM + bias + RoPE + layout
// C = hidden[2048x3584] @ Wqkv^T  (Wqkv rows = output features, 4608x3584)
// Block: 256 thr (4 waves), tile BM=128 BN=128 BK=64. Wave = 32 rows x 128 cols
// (full head width -> RoPE pairing d/d+64 in-register: acc tiles t and t+4).
#define LDSS 72
__launch_bounds__(256)
__global__ void gemm_qkv_rope(const short* __restrict__ A, const short* __restrict__ Bw,
                              const float* __restrict__ bq, const float* __restrict__ bk,
                              const float* __restrict__ bv,
                              const float* __restrict__ cosb, const float* __restrict__ sinb,
                              short* __restrict__ qo, short* __restrict__ ko, short* __restrict__ vto)
{
    __shared__ short ldsA[128*LDSS];
    __shared__ short ldsB[128*LDSS];
    const int tid  = threadIdx.x;
    const int wave = tid >> 6, lane = tid & 63;
    const int lq   = lane >> 4, l16 = lane & 15;
    const int m0   = blockIdx.y * 128, n0 = blockIdx.x * 128;

    f32x4 acc[2][8];
    #pragma unroll
    for (int i = 0; i < 2; i++)
        #pragma unroll
        for (int j = 0; j < 8; j++) acc[i][j] = (f32x4){0.f,0.f,0.f,0.f};

    for (int k0 = 0; k0 < HID; k0 += 64) {
        __syncthreads();
        #pragma unroll
        for (int i = 0; i < 4; i++) {
            int idx = tid + i*256;
            int row = idx >> 3, kc = (idx & 7) << 3;
            *(bf16x8*)&ldsA[row*LDSS + kc] = *(const bf16x8*)&A[(size_t)(m0+row)*HID + k0 + kc];
            *(bf16x8*)&ldsB[row*LDSS + kc] = *(const bf16x8*)&Bw[(size_t)(n0+row)*HID + k0 + kc];
        }
        __syncthreads();
        #pragma unroll
        for (int ks = 0; ks < 2; ks++) {
            bf16x8 af[2], bfr[8];
            #pragma unroll
            for (int mi = 0; mi < 2; mi++)
                af[mi] = *(bf16x8*)&ldsA[(wave*32 + mi*16 + l16)*LDSS + ks*32 + lq*8];
            #pragma unroll
            for (int ti = 0; ti < 8; ti++)
                bfr[ti] = *(bf16x8*)&ldsB[(ti*16 + l16)*LDSS + ks*32 + lq*8];
            #pragma unroll
            for (int mi = 0; mi < 2; mi++)
                #pragma unroll
                for (int ti = 0; ti < 8; ti++)
                    acc[mi][ti] = __builtin_amdgcn_mfma_f32_16x16x32_bf16(af[mi], bfr[ti], acc[mi][ti], 0,0,0);
        }
    }

    // Epilogue: bias + RoPE + scatter to per-head layouts.
    if (n0 < KOFF) {               // Q region
        int h = n0 >> 7;
        #pragma unroll
        for (int mi = 0; mi < 2; mi++)
            #pragma unroll
            for (int r = 0; r < 4; r++) {
                int s = m0 + wave*32 + mi*16 + lq*4 + r;
                size_t base = ((size_t)h*SEQ + s)*HD;
                #pragma unroll
                for (int t = 0; t < 4; t++) {
                    int d = t*16 + l16;
                    float c  = cosb[s*HD + d];
                    float sn = sinb[s*HD + d];
                    float x0 = acc[mi][t  ][r] + bq[n0 + t*16 + l16];
                    float x1 = acc[mi][t+4][r] + bq[n0 + 64 + t*16 + l16];
                    qo[base + d]      = f2bf((x0*c - x1*sn) * QSCALE);
                    qo[base + d + 64] = f2bf((x1*c + x0*sn) * QSCALE);
                }
            }
    } else if (n0 < VOFF) {        // K region
        int h = (n0 - KOFF) >> 7;
        #pragma unroll
        for (int mi = 0; mi < 2; mi++)
            #pragma unroll
            for (int r = 0; r < 4; r++) {
                int s = m0 + wave*32 + mi*16 + lq*4 + r;
                size_t base = ((size_t)h*SEQ + s)*HD;
                #pragma unroll
                for (int t = 0; t < 4; t++) {
                    int d = t*16 + l16;
                    float c  = cosb[s*HD + d];
                    float sn = sinb[s*HD + d];
                    float x0 = acc[mi][t  ][r] + bk[n0 - KOFF + t*16 + l16];
                    float x1 = acc[mi][t+4][r] + bk[n0 - KOFF + 64 + t*16 + l16];
                    ko[base + d]      = f2bf(x0*c - x1*sn);
                    ko[base + d + 64] = f2bf(x1*c + x0*sn);
                }
            }
    } else {                       // V region -> transposed store vt[h][d][s]
        int h = (n0 - VOFF) >> 7;
        #pragma unroll
        for (int mi = 0; mi < 2; mi++)
            #pragma unroll
            for (int r = 0; r < 4; r++) {
                int s = m0 + wave*32 + mi*16 + lq*4 + r;
                #pragma unroll
                for (int t = 0; t < 8; t++) {
                    int d = t*16 + l16;
                    float v = acc[mi][t][r] + bv[n0 - VOFF + t*16 + l16];
                    vto[((size_t)h*HD + d)*SEQ + s] = f2bf(v);
                }
            }
    }
}

// ---------------------------------------------------------------- flash attention
// Block 256 thr = 4 waves; each wave owns 16 q-rows of one head. Causal, online softmax.
// Q pre-scaled by 1/sqrt(d). K frags + Vt frags loaded straight from global (L2).
__launch_bounds__(256)
__global__ void attn_kernel(const short* __restrict__ q, const short* __restrict__ k,
                            const short* __restrict__ vt, short* __restrict__ out)
{
    const int h = blockIdx.y, hkv = h / 7;
    const int wave = threadIdx.x >> 6, lane = threadIdx.x & 63;
    const int lq = lane >> 4, l16 = lane & 15;
    const int q0 = blockIdx.x * 64 + wave * 16;

    const short* Q  = q  + (size_t)h   * SEQ * HD;
    const short* Kp = k  + (size_t)hkv * SEQ * HD;
    const short* VT = vt + (size_t)hkv * HD * SEQ;

    __shared__ short pbuf[4][16*40];
    short* P = &pbuf[wave][0];

    bf16x8 qf[4];
    #pragma unroll
    for (int ks = 0; ks < 4; ks++)
        qf[ks] = *(const bf16x8*)&Q[(size_t)(q0 + l16)*HD + ks*32 + lq*8];

    f32x4 o[8];
    #pragma unroll
    for (int t = 0; t < 8; t++) o[t] = (f32x4){0.f,0.f,0.f,0.f};
    float m_[4] = {-INFINITY,-INFINITY,-INFINITY,-INFINITY};
    float l_[4] = {0.f,0.f,0.f,0.f};

    const int kmax = q0 + 16;
    for (int k0 = 0; k0 < kmax; k0 += 32) {
        f32x4 sc[2];
        sc[0] = (f32x4){0.f,0.f,0.f,0.f};
        sc[1] = (f32x4){0.f,0.f,0.f,0.f};
        #pragma unroll
        for (int nt = 0; nt < 2; nt++)
            #pragma unroll
            for (int ks = 0; ks < 4; ks++) {
                bf16x8 kf = *(const bf16x8*)&Kp[(size_t)(k0 + nt*16 + l16)*HD + ks*32 + lq*8];
                sc[nt] = __builtin_amdgcn_mfma_f32_16x16x32_bf16(qf[ks], kf, sc[nt], 0,0,0);
            }
        // causal mask
        #pragma unroll
        for (int nt = 0; nt < 2; nt++) {
            int col = k0 + nt*16 + l16;
            #pragma unroll
            for (int r = 0; r < 4; r++) {
                int row = q0 + lq*4 + r;
                if (col > row) sc[nt][r] = -INFINITY;
            }
        }
        // online softmax (per-row reduce across the 16 lanes of this quad-group)
        float alpha[4];
        #pragma unroll
        for (int r = 0; r < 4; r++) {
            float mx = fmaxf(sc[0][r], sc[1][r]);
            #pragma unroll
            for (int sft = 8; sft >= 1; sft >>= 1) mx = fmaxf(mx, __shfl_xor(mx, sft));
            float nm = fmaxf(m_[r], mx);
            alpha[r] = exp2f((m_[r] - nm) * LOG2E);
            m_[r] = nm;
            float p0 = exp2f((sc[0][r] - nm) * LOG2E);
            float p1 = exp2f((sc[1][r] - nm) * LOG2E);
            sc[0][r] = p0; sc[1][r] = p1;
            float sm = p0 + p1;
            #pragma unroll
            for (int sft = 8; sft >= 1; sft >>= 1) sm += __shfl_xor(sm, sft);
            l_[r] = l_[r]*alpha[r] + sm;
        }
        #pragma unroll
        for (int t = 0; t < 8; t++)
            #pragma unroll
            for (int r = 0; r < 4; r++) o[t][r] *= alpha[r];
        // P: C-layout -> A-layout via per-wave LDS round-trip
        #pragma unroll
        for (int r = 0; r < 4; r++) {
            P[(lq*4 + r)*40 + l16]      = f2bf(sc[0][r]);
            P[(lq*4 + r)*40 + 16 + l16] = f2bf(sc[1][r]);
        }
        asm volatile("s_waitcnt lgkmcnt(0)" ::: "memory");
        bf16x8 pf = *(bf16x8*)&P[l16*40 + lq*8];
        asm volatile("s_waitcnt lgkmcnt(0)" ::: "memory");
        // PV
        #pragma unroll
        for (int t = 0; t < 8; t++) {
            bf16x8 vf = *(const bf16x8*)&VT[(size_t)(t*16 + l16)*SEQ + k0 + lq*8];
            o[t] = __builtin_amdgcn_mfma_f32_16x16x32_bf16(pf, vf, o[t], 0,0,0);
        }
    }

    #pragma unroll
    for (int r = 0; r < 4; r++) {
        float inv = 1.0f / l_[r];
        int s = q0 + lq*4 + r;
        #pragma unroll
        for (int t = 0; t < 8; t++)
            out[(size_t)s*HID + h*HD + t*16 + l16] = f2bf(o[t][r]*inv);
    }
}

// ---------------------------------------------------------------- output GEMM (fp32 out, no bias)
__launch_bounds__(256)
__global__ void gemm_out(const short* __restrict__ A, const short* __restrict__ Bw,
                         float* __restrict__ C)
{
    __shared__ short ldsA[128*LDSS];
    __shared__ short ldsB[128*LDSS];
    const int tid  = threadIdx.x;
    const int wave = tid >> 6, lane = tid & 63;
    const int lq   = lane >> 4, l16 = lane & 15;
    const int m0   = blockIdx.y * 128, n0 = blockIdx.x * 128;

    f32x4 acc[2][8];
    #pragma unroll
    for (int i = 0; i < 2; i++)
        #pragma unroll
        for (int j = 0; j < 8; j++) acc[i][j] = (f32x4){0.f,0.f,0.f,0.f};

    for (int k0 = 0; k0 < HID; k0 += 64) {
        __syncthreads();
        #pragma unroll
        for (int i = 0; i < 4; i++) {
            int idx = tid + i*256;
            int row = idx >> 3, kc = (idx & 7) << 3;
            *(bf16x8*)&ldsA[row*LDSS + kc] = *(const bf16x8*)&A[(size_t)(m0+row)*HID + k0 + kc];
            *(bf16x8*)&ldsB[row*LDSS + kc] = *(const bf16x8*)&Bw[(size_t)(n0+row)*HID + k0 + kc];
        }
        __syncthreads();
        #pragma unroll
        for (int ks = 0; ks < 2; ks++) {
            bf16x8 af[2], bfr[8];
            #pragma unroll
            for (int mi = 0; mi < 2; mi++)
                af[mi] = *(bf16x8*)&ldsA[(wave*32 + mi*16 + l16)*LDSS + ks*32 + lq*8];
            #pragma unroll
            for (int ti = 0; ti < 8; ti++)
                bfr[ti] = *(bf16x8*)&ldsB[(ti*16 + l16)*LDSS + ks*32 + lq*8];
            #pragma unroll
            for (int mi = 0; mi < 2; mi++)
                #pragma unroll
                for (int ti = 0; ti < 8; ti++)
                    acc[mi][ti] = __builtin_amdgcn_mfma_f32_16x16x32_bf16(af[mi], bfr[ti], acc[mi][ti], 0,0,0);
        }
    }

    #pragma unroll
    for (int mi = 0; mi < 2; mi++)
        #pragma unroll
        for (int r = 0; r < 4; r++) {
            int s = m0 + wave*32 + mi*16 + lq*4 + r;
            #pragma unroll
            for (int t = 0; t < 8; t++)
                C[(size_t)s*HID + n0 + t*16 + l16] = acc[mi][t][r];
        }
}

// ---------------------------------------------------------------- launcher
extern "C" void kernel_launch(void* const* d_in, const int* in_sizes, int n_in,
                              void* d_out, int out_size, void* d_ws, size_t ws_size,
                              hipStream_t stream) {
    const float* hidden = (const float*)d_in[0];
    const float* cosb   = (const float*)d_in[1];
    const float* sinb   = (const float*)d_in[2];
    const float* Wq     = (const float*)d_in[3];
    const float* bq     = (const float*)d_in[4];
    const float* Wk     = (const float*)d_in[5];
    const float* bk     = (const float*)d_in[6];
    const float* Wv     = (const float*)d_in[7];
    const float* bv     = (const float*)d_in[8];
    const float* Wo     = (const float*)d_in[9];
    float* out = (float*)d_out;

    char* ws = (char*)d_ws;
    short* hid_bf  = (short*)(ws);                         // 2048*3584*2  = 14,680,064
    short* wqkv_bf = (short*)(ws + 14680064);              // 4608*3584*2  = 33,030,144
    short* wo_bf   = (short*)(ws + 47710208);              // 3584*3584*2  = 25,690,112
    short* q_bf    = (short*)(ws + 73400320);              // 28*2048*128*2= 14,680,064
    short* k_bf    = (short*)(ws + 88080384);              //  4*2048*128*2=  2,097,152
    short* vt_bf   = (short*)(ws + 90177536);              //  4*128*2048*2=  2,097,152
    short* at_bf   = (short*)(ws + 92274688);              // 2048*3584*2  = 14,680,064

    auto cvt = [&](const float* s, short* d, size_t n){
        int n8 = (int)(n/8);
        cvt_f32_bf16<<<dim3((n8+255)/256), dim3(256), 0, stream>>>(s, d, n8);
    };
    cvt(hidden, hid_bf,  (size_t)SEQ*HID);
    cvt(Wq, wqkv_bf,                      (size_t)3584*HID);
    cvt(Wk, wqkv_bf + (size_t)3584*HID,   (size_t)512*HID);
    cvt(Wv, wqkv_bf + (size_t)4096*HID,   (size_t)512*HID);
    cvt(Wo, wo_bf,                        (size_t)3584*HID);

    gemm_qkv_rope<<<dim3(36,16), dim3(256), 0, stream>>>(hid_bf, wqkv_bf, bq, bk, bv,
                                                         cosb, sinb, q_bf, k_bf, vt_bf);
    attn_kernel<<<dim3(32,28), dim3(256), 0, stream>>>(q_bf, k_bf, vt_bf, at_bf);
    gemm_out<<<dim3(28,16), dim3(256), 0, stream>>>(at_bf, wo_bf, out);
}

// Round 3
// 597.190 us; speedup vs baseline: 1.6105x; 1.6105x over previous
//
#include <hip/hip_runtime.h>
#include <hip/hip_bf16.h>
#include <cmath>
#include <cstdint>

// Problem constants
#define SEQ    2048
#define HID    3584
#define NH     28
#define NKV    4
#define HD     128
#define NTOT   4608          // 3584 q + 512 k + 512 v
#define KOFF   3584
#define VOFF   4096
#define QSCALE 0.08838834764831845f   // 1/sqrt(128)
#define LOG2E  1.4426950408889634f

typedef __attribute__((ext_vector_type(8))) short bf16x8;
typedef __attribute__((ext_vector_type(4))) float f32x4;

__device__ inline short f2bf(float f){
    union { float f; uint32_t u; } c; c.f = f;
    uint32_t u = c.u;
    uint32_t r = (u + 0x7fffu + ((u >> 16) & 1u)) >> 16;
    return (short)r;
}

// ---------------------------------------------------------------- convert
__global__ void cvt_f32_bf16(const float* __restrict__ src, short* __restrict__ dst, int n8){
    int i = blockIdx.x * blockDim.x + threadIdx.x;
    if (i >= n8) return;
    float4 a = ((const float4*)src)[2*i];
    float4 b = ((const float4*)src)[2*i+1];
    bf16x8 o;
    o[0]=f2bf(a.x); o[1]=f2bf(a.y); o[2]=f2bf(a.z); o[3]=f2bf(a.w);
    o[4]=f2bf(b.x); o[5]=f2bf(b.y); o[6]=f2bf(b.z); o[7]=f2bf(b.w);
    ((bf16x8*)dst)[i] = o;
}

// ---------------------------------------------------------------- QKV GEMM + bias + RoPE + layout
#define LDSS 72
__launch_bounds__(256)
__global__ void gemm_qkv_rope(const short* __restrict__ A, const short* __restrict__ Bw,
                              const float* __restrict__ bq, const float* __restrict__ bk,
                              const float* __restrict__ bv,
                              const float* __restrict__ cosb, const float* __restrict__ sinb,
                              short* __restrict__ qo, short* __restrict__ ko, short* __restrict__ vto)
{
    __shared__ short ldsA[128*LDSS];
    __shared__ short ldsB[128*LDSS];
    const int tid  = threadIdx.x;
    const int wave = tid >> 6, lane = tid & 63;
    const int lq   = lane >> 4, l16 = lane & 15;
    const int m0   = blockIdx.y * 128, n0 = blockIdx.x * 128;

    f32x4 acc[2][8];
    #pragma unroll
    for (int i = 0; i < 2; i++)
        #pragma unroll
        for (int j = 0; j < 8; j++) acc[i][j] = (f32x4){0.f,0.f,0.f,0.f};

    for (int k0 = 0; k0 < HID; k0 += 64) {
        __syncthreads();
        #pragma unroll
        for (int i = 0; i < 4; i++) {
            int idx = tid + i*256;
            int row = idx >> 3, kc = (idx & 7) << 3;
            *(bf16x8*)&ldsA[row*LDSS + kc] = *(const bf16x8*)&A[(size_t)(m0+row)*HID + k0 + kc];
            *(bf16x8*)&ldsB[row*LDSS + kc] = *(const bf16x8*)&Bw[(size_t)(n0+row)*HID + k0 + kc];
        }
        __syncthreads();
        #pragma unroll
        for (int ks = 0; ks < 2; ks++) {
            bf16x8 af[2], bfr[8];
            #pragma unroll
            for (int mi = 0; mi < 2; mi++)
                af[mi] = *(bf16x8*)&ldsA[(wave*32 + mi*16 + l16)*LDSS + ks*32 + lq*8];
            #pragma unroll
            for (int ti = 0; ti < 8; ti++)
                bfr[ti] = *(bf16x8*)&ldsB[(ti*16 + l16)*LDSS + ks*32 + lq*8];
            #pragma unroll
            for (int mi = 0; mi < 2; mi++)
                #pragma unroll
                for (int ti = 0; ti < 8; ti++)
                    acc[mi][ti] = __builtin_amdgcn_mfma_f32_16x16x32_bf16(af[mi], bfr[ti], acc[mi][ti], 0,0,0);
        }
    }

    if (n0 < KOFF) {               // Q region
        int h = n0 >> 7;
        #pragma unroll
        for (int mi = 0; mi < 2; mi++)
            #pragma unroll
            for (int r = 0; r < 4; r++) {
                int s = m0 + wave*32 + mi*16 + lq*4 + r;
                size_t base = ((size_t)h*SEQ + s)*HD;
                #pragma unroll
                for (int t = 0; t < 4; t++) {
                    int d = t*16 + l16;
                    float c  = cosb[s*HD + d];
                    float sn = sinb[s*HD + d];
                    float x0 = acc[mi][t  ][r] + bq[n0 + t*16 + l16];
                    float x1 = acc[mi][t+4][r] + bq[n0 + 64 + t*16 + l16];
                    qo[base + d]      = f2bf((x0*c - x1*sn) * QSCALE);
                    qo[base + d + 64] = f2bf((x1*c + x0*sn) * QSCALE);
                }
            }
    } else if (n0 < VOFF) {        // K region
        int h = (n0 - KOFF) >> 7;
        #pragma unroll
        for (int mi = 0; mi < 2; mi++)
            #pragma unroll
            for (int r = 0; r < 4; r++) {
                int s = m0 + wave*32 + mi*16 + lq*4 + r;
                size_t base = ((size_t)h*SEQ + s)*HD;
                #pragma unroll
                for (int t = 0; t < 4; t++) {
                    int d = t*16 + l16;
                    float c  = cosb[s*HD + d];
                    float sn = sinb[s*HD + d];
                    float x0 = acc[mi][t  ][r] + bk[n0 - KOFF + t*16 + l16];
                    float x1 = acc[mi][t+4][r] + bk[n0 - KOFF + 64 + t*16 + l16];
                    ko[base + d]      = f2bf(x0*c - x1*sn);
                    ko[base + d + 64] = f2bf(x1*c + x0*sn);
                }
            }
    } else {                       // V region -> transposed store vt[h][d][s]
        int h = (n0 - VOFF) >> 7;
        #pragma unroll
        for (int mi = 0; mi < 2; mi++)
            #pragma unroll
            for (int r = 0; r < 4; r++) {
                int s = m0 + wave*32 + mi*16 + lq*4 + r;
                #pragma unroll
                for (int t = 0; t < 8; t++) {
                    int d = t*16 + l16;
                    float v = acc[mi][t][r] + bv[n0 - VOFF + t*16 + l16];
                    vto[((size_t)h*HD + d)*SEQ + s] = f2bf(v);
                }
            }
    }
}

// ---------------------------------------------------------------- flash attention v3
// Block = 128 q-rows x 1 head, 4 waves. Wave owns 2 m-tiles: rows w*16 and 64+w*16.
// K-chunk = 64 keys staged in LDS (K 64x128, V^T 128x64). STRAIGHT-LINE body:
// no activity guards, mask applied unconditionally (idempotent; fully-masked
// chunks give alpha=1, p=0 -- NaN-safe since chunk 0 always has unmasked cols).
// P C->A layout transform via LDS with a real __syncthreads() fence.
#define KP 136
#define VP 72
__launch_bounds__(256)
__global__ void attn_kernel(const short* __restrict__ q, const short* __restrict__ k,
                            const short* __restrict__ vt, short* __restrict__ out)
{
    const int b  = blockIdx.x;
    const int h  = b % NH;
    const int qt = 15 - (b / NH);          // heavy q-tiles dispatched first
    const int q0b = qt * 128;
    const int hkv = h / 7;

    const int tid = threadIdx.x;
    const int wave = tid >> 6, lane = tid & 63;
    const int lq = lane >> 4, l16 = lane & 15;

    const short* Q  = q  + (size_t)h   * SEQ * HD;
    const short* Kp = k  + (size_t)hkv * SEQ * HD;
    const short* VT = vt + (size_t)hkv * HD * SEQ;

    __shared__ short kbuf[64*KP];
    __shared__ short vbuf[128*VP];
    __shared__ short pbuf[4][2][16*VP];

    const int qr[2] = { q0b + wave*16, q0b + 64 + wave*16 };

    bf16x8 qf[2][4];
    #pragma unroll
    for (int m = 0; m < 2; m++)
        #pragma unroll
        for (int ks = 0; ks < 4; ks++)
            qf[m][ks] = *(const bf16x8*)&Q[(size_t)(qr[m] + l16)*HD + ks*32 + lq*8];

    f32x4 o[2][8];
    #pragma unroll
    for (int m = 0; m < 2; m++)
        #pragma unroll
        for (int t = 0; t < 8; t++) o[m][t] = (f32x4){0.f,0.f,0.f,0.f};
    float m_[2][4] = {{-INFINITY,-INFINITY,-INFINITY,-INFINITY},
                      {-INFINITY,-INFINITY,-INFINITY,-INFINITY}};
    float l_[2][4] = {{0.f,0.f,0.f,0.f},{0.f,0.f,0.f,0.f}};

    const int nchunk = (q0b >> 6) + 2;
    for (int ci = 0; ci < nchunk; ci++) {
        const int k0 = ci << 6;
        // ---- stage K (64x128) and V^T (128x64) ----
        __syncthreads();
        #pragma unroll
        for (int i = 0; i < 4; i++) {
            int c = tid + i*256;             // 1024 chunks of 8 shorts
            int row = c >> 4, pos = c & 15;
            *(bf16x8*)&kbuf[row*KP + pos*8] =
                *(const bf16x8*)&Kp[(size_t)(k0 + row)*HD + pos*8];
        }
        #pragma unroll
        for (int i = 0; i < 4; i++) {
            int c = tid + i*256;
            int d = c >> 3, pos = c & 7;
            *(bf16x8*)&vbuf[d*VP + pos*8] =
                *(const bf16x8*)&VT[(size_t)d*SEQ + k0 + pos*8];
        }
        __syncthreads();

        // ---- QK^T: kf loaded once, feeds both m-tiles ----
        f32x4 sc[2][4];
        #pragma unroll
        for (int m = 0; m < 2; m++)
            #pragma unroll
            for (int nt = 0; nt < 4; nt++) sc[m][nt] = (f32x4){0.f,0.f,0.f,0.f};
        #pragma unroll
        for (int nt = 0; nt < 4; nt++)
            #pragma unroll
            for (int ks = 0; ks < 4; ks++) {
                bf16x8 kf = *(bf16x8*)&kbuf[(nt*16 + l16)*KP + ks*32 + lq*8];
                sc[0][nt] = __builtin_amdgcn_mfma_f32_16x16x32_bf16(qf[0][ks], kf, sc[0][nt], 0,0,0);
                sc[1][nt] = __builtin_amdgcn_mfma_f32_16x16x32_bf16(qf[1][ks], kf, sc[1][nt], 0,0,0);
            }

        // ---- causal mask (unconditional) + online softmax + P store ----
        #pragma unroll
        for (int m = 0; m < 2; m++) {
            #pragma unroll
            for (int nt = 0; nt < 4; nt++) {
                int col = k0 + nt*16 + l16;
                #pragma unroll
                for (int r = 0; r < 4; r++) {
                    int row = qr[m] + lq*4 + r;
                    if (col > row) sc[m][nt][r] = -INFINITY;
                }
            }
            float alpha[4];
            #pragma unroll
            for (int r = 0; r < 4; r++) {
                float mx = fmaxf(fmaxf(sc[m][0][r], sc[m][1][r]),
                                 fmaxf(sc[m][2][r], sc[m][3][r]));
                #pragma unroll
                for (int sft = 8; sft >= 1; sft >>= 1) mx = fmaxf(mx, __shfl_xor(mx, sft));
                float nm = fmaxf(m_[m][r], mx);
                alpha[r] = exp2f((m_[m][r] - nm) * LOG2E);
                m_[m][r] = nm;
                float sm = 0.f;
                #pragma unroll
                for (int nt = 0; nt < 4; nt++) {
                    float p = exp2f((sc[m][nt][r] - nm) * LOG2E);
                    sc[m][nt][r] = p;
                    sm += p;
                }
                #pragma unroll
                for (int sft = 8; sft >= 1; sft >>= 1) sm += __shfl_xor(sm, sft);
                l_[m][r] = l_[m][r]*alpha[r] + sm;
            }
            #pragma unroll
            for (int t = 0; t < 8; t++)
                #pragma unroll
                for (int r = 0; r < 4; r++) o[m][t][r] *= alpha[r];
            #pragma unroll
            for (int r = 0; r < 4; r++)
                #pragma unroll
                for (int nt = 0; nt < 4; nt++)
                    pbuf[wave][m][(lq*4 + r)*VP + nt*16 + l16] = f2bf(sc[m][nt][r]);
        }
        __syncthreads();             // P visible (and staging of next chunk gated anyway)

        bf16x8 pf[2][2];
        #pragma unroll
        for (int m = 0; m < 2; m++)
            #pragma unroll
            for (int kk = 0; kk < 2; kk++)
                pf[m][kk] = *(bf16x8*)&pbuf[wave][m][l16*VP + kk*32 + lq*8];

        // ---- PV: vf loaded once, feeds both m-tiles ----
        #pragma unroll
        for (int t = 0; t < 8; t++)
            #pragma unroll
            for (int kk = 0; kk < 2; kk++) {
                bf16x8 vf = *(bf16x8*)&vbuf[(t*16 + l16)*VP + kk*32 + lq*8];
                o[0][t] = __builtin_amdgcn_mfma_f32_16x16x32_bf16(pf[0][kk], vf, o[0][t], 0,0,0);
                o[1][t] = __builtin_amdgcn_mfma_f32_16x16x32_bf16(pf[1][kk], vf, o[1][t], 0,0,0);
            }
    }

    #pragma unroll
    for (int m = 0; m < 2; m++)
        #pragma unroll
        for (int r = 0; r < 4; r++) {
            float inv = 1.0f / l_[m][r];
            int s = qr[m] + lq*4 + r;
            #pragma unroll
            for (int t = 0; t < 8; t++)
                out[(size_t)s*HID + h*HD + t*16 + l16] = f2bf(o[m][t][r]*inv);
        }
}

// ---------------------------------------------------------------- output GEMM (fp32 out, no bias)
__launch_bounds__(256)
__global__ void gemm_out(const short* __restrict__ A, const short* __restrict__ Bw,
                         float* __restrict__ C)
{
    __shared__ short ldsA[128*LDSS];
    __shared__ short ldsB[128*LDSS];
    const int tid  = threadIdx.x;
    const int wave = tid >> 6, lane = tid & 63;
    const int lq   = lane >> 4, l16 = lane & 15;
    const int m0   = blockIdx.y * 128, n0 = blockIdx.x * 128;

    f32x4 acc[2][8];
    #pragma unroll
    for (int i = 0; i < 2; i++)
        #pragma unroll
        for (int j = 0; j < 8; j++) acc[i][j] = (f32x4){0.f,0.f,0.f,0.f};

    for (int k0 = 0; k0 < HID; k0 += 64) {
        __syncthreads();
        #pragma unroll
        for (int i = 0; i < 4; i++) {
            int idx = tid + i*256;
            int row = idx >> 3, kc = (idx & 7) << 3;
            *(bf16x8*)&ldsA[row*LDSS + kc] = *(const bf16x8*)&A[(size_t)(m0+row)*HID + k0 + kc];
            *(bf16x8*)&ldsB[row*LDSS + kc] = *(const bf16x8*)&Bw[(size_t)(n0+row)*HID + k0 + kc];
        }
        __syncthreads();
        #pragma unroll
        for (int ks = 0; ks < 2; ks++) {
            bf16x8 af[2], bfr[8];
            #pragma unroll
            for (int mi = 0; mi < 2; mi++)
                af[mi] = *(bf16x8*)&ldsA[(wave*32 + mi*16 + l16)*LDSS + ks*32 + lq*8];
            #pragma unroll
            for (int ti = 0; ti < 8; ti++)
                bfr[ti] = *(bf16x8*)&ldsB[(ti*16 + l16)*LDSS + ks*32 + lq*8];
            #pragma unroll
            for (int mi = 0; mi < 2; mi++)
                #pragma unroll
                for (int ti = 0; ti < 8; ti++)
                    acc[mi][ti] = __builtin_amdgcn_mfma_f32_16x16x32_bf16(af[mi], bfr[ti], acc[mi][ti], 0,0,0);
        }
    }

    #pragma unroll
    for (int mi = 0; mi < 2; mi++)
        #pragma unroll
        for (int r = 0; r < 4; r++) {
            int s = m0 + wave*32 + mi*16 + lq*4 + r;
            #pragma unroll
            for (int t = 0; t < 8; t++)
                C[(size_t)s*HID + n0 + t*16 + l16] = acc[mi][t][r];
        }
}

// ---------------------------------------------------------------- launcher
extern "C" void kernel_launch(void* const* d_in, const int* in_sizes, int n_in,
                              void* d_out, int out_size, void* d_ws, size_t ws_size,
                              hipStream_t stream) {
    const float* hidden = (const float*)d_in[0];
    const float* cosb   = (const float*)d_in[1];
    const float* sinb   = (const float*)d_in[2];
    const float* Wq     = (const float*)d_in[3];
    const float* bq     = (const float*)d_in[4];
    const float* Wk     = (const float*)d_in[5];
    const float* bk     = (const float*)d_in[6];
    const float* Wv     = (const float*)d_in[7];
    const float* bv     = (const float*)d_in[8];
    const float* Wo     = (const float*)d_in[9];
    float* out = (float*)d_out;

    char* ws = (char*)d_ws;
    short* hid_bf  = (short*)(ws);                         // 2048*3584*2  = 14,680,064
    short* wqkv_bf = (short*)(ws + 14680064);              // 4608*3584*2  = 33,030,144
    short* wo_bf   = (short*)(ws + 47710208);              // 3584*3584*2  = 25,690,112
    short* q_bf    = (short*)(ws + 73400320);              // 28*2048*128*2= 14,680,064
    short* k_bf    = (short*)(ws + 88080384);              //  4*2048*128*2=  2,097,152
    short* vt_bf   = (short*)(ws + 90177536);              //  4*128*2048*2=  2,097,152
    short* at_bf   = (short*)(ws + 92274688);              // 2048*3584*2  = 14,680,064

    auto cvt = [&](const float* s, short* d, size_t n){
        int n8 = (int)(n/8);
        cvt_f32_bf16<<<dim3((n8+255)/256), dim3(256), 0, stream>>>(s, d, n8);
    };
    cvt(hidden, hid_bf,  (size_t)SEQ*HID);
    cvt(Wq, wqkv_bf,                      (size_t)3584*HID);
    cvt(Wk, wqkv_bf + (size_t)3584*HID,   (size_t)512*HID);
    cvt(Wv, wqkv_bf + (size_t)4096*HID,   (size_t)512*HID);
    cvt(Wo, wo_bf,                        (size_t)3584*HID);

    gemm_qkv_rope<<<dim3(36,16), dim3(256), 0, stream>>>(hid_bf, wqkv_bf, bq, bk, bv,
                                                         cosb, sinb, q_bf, k_bf, vt_bf);
    attn_kernel<<<dim3(448), dim3(256), 0, stream>>>(q_bf, k_bf, vt_bf, at_bf);
    gemm_out<<<dim3(28,16), dim3(256), 0, stream>>>(at_bf, wo_bf, out);
}

// Round 4
// 575.937 us; speedup vs baseline: 1.6700x; 1.0369x over previous
//
#include <hip/hip_runtime.h>
#include <hip/hip_bf16.h>
#include <cmath>
#include <cstdint>

// Problem constants
#define SEQ    2048
#define HID    3584
#define NH     28
#define NKV    4
#define HD     128
#define NTOT   4608          // 3584 q + 512 k + 512 v
#define KOFF   3584
#define VOFF   4096
#define QSCALE 0.08838834764831845f   // 1/sqrt(128)
#define LOG2E  1.4426950408889634f

typedef __attribute__((ext_vector_type(8))) short bf16x8;
typedef __attribute__((ext_vector_type(4))) float f32x4;

__device__ inline short f2bf(float f){
    union { float f; uint32_t u; } c; c.f = f;
    uint32_t u = c.u;
    uint32_t r = (u + 0x7fffu + ((u >> 16) & 1u)) >> 16;
    return (short)r;
}

// async global->LDS, 16B per lane; LDS dest = wave-uniform base + lane*16
__device__ __forceinline__ void gl_lds16(const short* g, short* l) {
    __builtin_amdgcn_global_load_lds(
        (const __attribute__((address_space(1))) void*)g,
        (__attribute__((address_space(3))) void*)l,
        16, 0, 0);
}

// ---------------------------------------------------------------- convert
__global__ void cvt_f32_bf16(const float* __restrict__ src, short* __restrict__ dst, int n8){
    int i = blockIdx.x * blockDim.x + threadIdx.x;
    if (i >= n8) return;
    float4 a = ((const float4*)src)[2*i];
    float4 b = ((const float4*)src)[2*i+1];
    bf16x8 o;
    o[0]=f2bf(a.x); o[1]=f2bf(a.y); o[2]=f2bf(a.z); o[3]=f2bf(a.w);
    o[4]=f2bf(b.x); o[5]=f2bf(b.y); o[6]=f2bf(b.z); o[7]=f2bf(b.w);
    ((bf16x8*)dst)[i] = o;
}

// ---------------------------------------------------------------- QKV GEMM + bias + RoPE + layout
// m97 recipe: global_load_lds width=16, unpadded 128x64 tiles, XOR chunk swizzle
// (LDS chunk c of row r holds global chunk c^(r&7)) -> 2-way banks on b128 reads.
__launch_bounds__(256)
__global__ void gemm_qkv_rope(const short* __restrict__ A, const short* __restrict__ Bw,
                              const float* __restrict__ bq, const float* __restrict__ bk,
                              const float* __restrict__ bv,
                              const float* __restrict__ cosb, const float* __restrict__ sinb,
                              short* __restrict__ qo, short* __restrict__ ko, short* __restrict__ vto)
{
    __shared__ short ldsA[128*64];
    __shared__ short ldsB[128*64];
    const int tid  = threadIdx.x;
    const int wave = tid >> 6, lane = tid & 63;
    const int lq   = lane >> 4, l16 = lane & 15;
    const int m0   = blockIdx.y * 128, n0 = blockIdx.x * 128;

    const int lrow = lane >> 3;          // 0..7 (row within wave's 8-row group)
    const int gchk = ((lane & 7) ^ lrow) << 3;   // swizzled 16B-chunk offset (shorts)

    f32x4 acc[2][8];
    #pragma unroll
    for (int i = 0; i < 2; i++)
        #pragma unroll
        for (int j = 0; j < 8; j++) acc[i][j] = (f32x4){0.f,0.f,0.f,0.f};

    for (int k0 = 0; k0 < HID; k0 += 64) {
        __syncthreads();
        #pragma unroll
        for (int j = 0; j < 4; j++) {
            int r = j*32 + wave*8 + lrow;
            gl_lds16(&A[(size_t)(m0 + r)*HID + k0 + gchk], &ldsA[(j*32 + wave*8)*64]);
            gl_lds16(&Bw[(size_t)(n0 + r)*HID + k0 + gchk], &ldsB[(j*32 + wave*8)*64]);
        }
        __syncthreads();
        #pragma unroll
        for (int ks = 0; ks < 2; ks++) {
            bf16x8 af[2], bfr[8];
            #pragma unroll
            for (int mi = 0; mi < 2; mi++) {
                int row = wave*32 + mi*16 + l16;
                af[mi] = *(bf16x8*)&ldsA[row*64 + (((ks*4 + lq) ^ (l16 & 7)) << 3)];
            }
            #pragma unroll
            for (int ti = 0; ti < 8; ti++) {
                int row = ti*16 + l16;
                bfr[ti] = *(bf16x8*)&ldsB[row*64 + (((ks*4 + lq) ^ (l16 & 7)) << 3)];
            }
            #pragma unroll
            for (int mi = 0; mi < 2; mi++)
                #pragma unroll
                for (int ti = 0; ti < 8; ti++)
                    acc[mi][ti] = __builtin_amdgcn_mfma_f32_16x16x32_bf16(af[mi], bfr[ti], acc[mi][ti], 0,0,0);
        }
    }

    if (n0 < KOFF) {               // Q region
        int h = n0 >> 7;
        #pragma unroll
        for (int mi = 0; mi < 2; mi++)
            #pragma unroll
            for (int r = 0; r < 4; r++) {
                int s = m0 + wave*32 + mi*16 + lq*4 + r;
                size_t base = ((size_t)h*SEQ + s)*HD;
                #pragma unroll
                for (int t = 0; t < 4; t++) {
                    int d = t*16 + l16;
                    float c  = cosb[s*HD + d];
                    float sn = sinb[s*HD + d];
                    float x0 = acc[mi][t  ][r] + bq[n0 + t*16 + l16];
                    float x1 = acc[mi][t+4][r] + bq[n0 + 64 + t*16 + l16];
                    qo[base + d]      = f2bf((x0*c - x1*sn) * QSCALE);
                    qo[base + d + 64] = f2bf((x1*c + x0*sn) * QSCALE);
                }
            }
    } else if (n0 < VOFF) {        // K region
        int h = (n0 - KOFF) >> 7;
        #pragma unroll
        for (int mi = 0; mi < 2; mi++)
            #pragma unroll
            for (int r = 0; r < 4; r++) {
                int s = m0 + wave*32 + mi*16 + lq*4 + r;
                size_t base = ((size_t)h*SEQ + s)*HD;
                #pragma unroll
                for (int t = 0; t < 4; t++) {
                    int d = t*16 + l16;
                    float c  = cosb[s*HD + d];
                    float sn = sinb[s*HD + d];
                    float x0 = acc[mi][t  ][r] + bk[n0 - KOFF + t*16 + l16];
                    float x1 = acc[mi][t+4][r] + bk[n0 - KOFF + 64 + t*16 + l16];
                    ko[base + d]      = f2bf(x0*c - x1*sn);
                    ko[base + d + 64] = f2bf(x1*c + x0*sn);
                }
            }
    } else {                       // V region -> transposed store vt[h][d][s]
        int h = (n0 - VOFF) >> 7;
        #pragma unroll
        for (int mi = 0; mi < 2; mi++)
            #pragma unroll
            for (int r = 0; r < 4; r++) {
                int s = m0 + wave*32 + mi*16 + lq*4 + r;
                #pragma unroll
                for (int t = 0; t < 8; t++) {
                    int d = t*16 + l16;
                    float v = acc[mi][t][r] + bv[n0 - VOFF + t*16 + l16];
                    vto[((size_t)h*HD + d)*SEQ + s] = f2bf(v);
                }
            }
    }
}

// ---------------------------------------------------------------- flash attention v3 (unchanged)
#define KP 136
#define VP 72
__launch_bounds__(256)
__global__ void attn_kernel(const short* __restrict__ q, const short* __restrict__ k,
                            const short* __restrict__ vt, short* __restrict__ out)
{
    const int b  = blockIdx.x;
    const int h  = b % NH;
    const int qt = 15 - (b / NH);          // heavy q-tiles dispatched first
    const int q0b = qt * 128;
    const int hkv = h / 7;

    const int tid = threadIdx.x;
    const int wave = tid >> 6, lane = tid & 63;
    const int lq = lane >> 4, l16 = lane & 15;

    const short* Q  = q  + (size_t)h   * SEQ * HD;
    const short* Kp = k  + (size_t)hkv * SEQ * HD;
    const short* VT = vt + (size_t)hkv * HD * SEQ;

    __shared__ short kbuf[64*KP];
    __shared__ short vbuf[128*VP];
    __shared__ short pbuf[4][2][16*VP];

    const int qr[2] = { q0b + wave*16, q0b + 64 + wave*16 };

    bf16x8 qf[2][4];
    #pragma unroll
    for (int m = 0; m < 2; m++)
        #pragma unroll
        for (int ks = 0; ks < 4; ks++)
            qf[m][ks] = *(const bf16x8*)&Q[(size_t)(qr[m] + l16)*HD + ks*32 + lq*8];

    f32x4 o[2][8];
    #pragma unroll
    for (int m = 0; m < 2; m++)
        #pragma unroll
        for (int t = 0; t < 8; t++) o[m][t] = (f32x4){0.f,0.f,0.f,0.f};
    float m_[2][4] = {{-INFINITY,-INFINITY,-INFINITY,-INFINITY},
                      {-INFINITY,-INFINITY,-INFINITY,-INFINITY}};
    float l_[2][4] = {{0.f,0.f,0.f,0.f},{0.f,0.f,0.f,0.f}};

    const int nchunk = (q0b >> 6) + 2;
    for (int ci = 0; ci < nchunk; ci++) {
        const int k0 = ci << 6;
        __syncthreads();
        #pragma unroll
        for (int i = 0; i < 4; i++) {
            int c = tid + i*256;             // 1024 chunks of 8 shorts
            int row = c >> 4, pos = c & 15;
            *(bf16x8*)&kbuf[row*KP + pos*8] =
                *(const bf16x8*)&Kp[(size_t)(k0 + row)*HD + pos*8];
        }
        #pragma unroll
        for (int i = 0; i < 4; i++) {
            int c = tid + i*256;
            int d = c >> 3, pos = c & 7;
            *(bf16x8*)&vbuf[d*VP + pos*8] =
                *(const bf16x8*)&VT[(size_t)d*SEQ + k0 + pos*8];
        }
        __syncthreads();

        f32x4 sc[2][4];
        #pragma unroll
        for (int m = 0; m < 2; m++)
            #pragma unroll
            for (int nt = 0; nt < 4; nt++) sc[m][nt] = (f32x4){0.f,0.f,0.f,0.f};
        #pragma unroll
        for (int nt = 0; nt < 4; nt++)
            #pragma unroll
            for (int ks = 0; ks < 4; ks++) {
                bf16x8 kf = *(bf16x8*)&kbuf[(nt*16 + l16)*KP + ks*32 + lq*8];
                sc[0][nt] = __builtin_amdgcn_mfma_f32_16x16x32_bf16(qf[0][ks], kf, sc[0][nt], 0,0,0);
                sc[1][nt] = __builtin_amdgcn_mfma_f32_16x16x32_bf16(qf[1][ks], kf, sc[1][nt], 0,0,0);
            }

        #pragma unroll
        for (int m = 0; m < 2; m++) {
            #pragma unroll
            for (int nt = 0; nt < 4; nt++) {
                int col = k0 + nt*16 + l16;
                #pragma unroll
                for (int r = 0; r < 4; r++) {
                    int row = qr[m] + lq*4 + r;
                    if (col > row) sc[m][nt][r] = -INFINITY;
                }
            }
            float alpha[4];
            #pragma unroll
            for (int r = 0; r < 4; r++) {
                float mx = fmaxf(fmaxf(sc[m][0][r], sc[m][1][r]),
                                 fmaxf(sc[m][2][r], sc[m][3][r]));
                #pragma unroll
                for (int sft = 8; sft >= 1; sft >>= 1) mx = fmaxf(mx, __shfl_xor(mx, sft));
                float nm = fmaxf(m_[m][r], mx);
                alpha[r] = exp2f((m_[m][r] - nm) * LOG2E);
                m_[m][r] = nm;
                float sm = 0.f;
                #pragma unroll
                for (int nt = 0; nt < 4; nt++) {
                    float p = exp2f((sc[m][nt][r] - nm) * LOG2E);
                    sc[m][nt][r] = p;
                    sm += p;
                }
                #pragma unroll
                for (int sft = 8; sft >= 1; sft >>= 1) sm += __shfl_xor(sm, sft);
                l_[m][r] = l_[m][r]*alpha[r] + sm;
            }
            #pragma unroll
            for (int t = 0; t < 8; t++)
                #pragma unroll
                for (int r = 0; r < 4; r++) o[m][t][r] *= alpha[r];
            #pragma unroll
            for (int r = 0; r < 4; r++)
                #pragma unroll
                for (int nt = 0; nt < 4; nt++)
                    pbuf[wave][m][(lq*4 + r)*VP + nt*16 + l16] = f2bf(sc[m][nt][r]);
        }
        __syncthreads();

        bf16x8 pf[2][2];
        #pragma unroll
        for (int m = 0; m < 2; m++)
            #pragma unroll
            for (int kk = 0; kk < 2; kk++)
                pf[m][kk] = *(bf16x8*)&pbuf[wave][m][l16*VP + kk*32 + lq*8];

        #pragma unroll
        for (int t = 0; t < 8; t++)
            #pragma unroll
            for (int kk = 0; kk < 2; kk++) {
                bf16x8 vf = *(bf16x8*)&vbuf[(t*16 + l16)*VP + kk*32 + lq*8];
                o[0][t] = __builtin_amdgcn_mfma_f32_16x16x32_bf16(pf[0][kk], vf, o[0][t], 0,0,0);
                o[1][t] = __builtin_amdgcn_mfma_f32_16x16x32_bf16(pf[1][kk], vf, o[1][t], 0,0,0);
            }
    }

    #pragma unroll
    for (int m = 0; m < 2; m++)
        #pragma unroll
        for (int r = 0; r < 4; r++) {
            float inv = 1.0f / l_[m][r];
            int s = qr[m] + lq*4 + r;
            #pragma unroll
            for (int t = 0; t < 8; t++)
                out[(size_t)s*HID + h*HD + t*16 + l16] = f2bf(o[m][t][r]*inv);
        }
}

// ---------------------------------------------------------------- output GEMM (fp32 out, no bias)
__launch_bounds__(256)
__global__ void gemm_out(const short* __restrict__ A, const short* __restrict__ Bw,
                         float* __restrict__ C)
{
    __shared__ short ldsA[128*64];
    __shared__ short ldsB[128*64];
    const int tid  = threadIdx.x;
    const int wave = tid >> 6, lane = tid & 63;
    const int lq   = lane >> 4, l16 = lane & 15;
    const int m0   = blockIdx.y * 128, n0 = blockIdx.x * 128;

    const int lrow = lane >> 3;
    const int gchk = ((lane & 7) ^ lrow) << 3;

    f32x4 acc[2][8];
    #pragma unroll
    for (int i = 0; i < 2; i++)
        #pragma unroll
        for (int j = 0; j < 8; j++) acc[i][j] = (f32x4){0.f,0.f,0.f,0.f};

    for (int k0 = 0; k0 < HID; k0 += 64) {
        __syncthreads();
        #pragma unroll
        for (int j = 0; j < 4; j++) {
            int r = j*32 + wave*8 + lrow;
            gl_lds16(&A[(size_t)(m0 + r)*HID + k0 + gchk], &ldsA[(j*32 + wave*8)*64]);
            gl_lds16(&Bw[(size_t)(n0 + r)*HID + k0 + gchk], &ldsB[(j*32 + wave*8)*64]);
        }
        __syncthreads();
        #pragma unroll
        for (int ks = 0; ks < 2; ks++) {
            bf16x8 af[2], bfr[8];
            #pragma unroll
            for (int mi = 0; mi < 2; mi++) {
                int row = wave*32 + mi*16 + l16;
                af[mi] = *(bf16x8*)&ldsA[row*64 + (((ks*4 + lq) ^ (l16 & 7)) << 3)];
            }
            #pragma unroll
            for (int ti = 0; ti < 8; ti++) {
                int row = ti*16 + l16;
                bfr[ti] = *(bf16x8*)&ldsB[row*64 + (((ks*4 + lq) ^ (l16 & 7)) << 3)];
            }
            #pragma unroll
            for (int mi = 0; mi < 2; mi++)
                #pragma unroll
                for (int ti = 0; ti < 8; ti++)
                    acc[mi][ti] = __builtin_amdgcn_mfma_f32_16x16x32_bf16(af[mi], bfr[ti], acc[mi][ti], 0,0,0);
        }
    }

    #pragma unroll
    for (int mi = 0; mi < 2; mi++)
        #pragma unroll
        for (int r = 0; r < 4; r++) {
            int s = m0 + wave*32 + mi*16 + lq*4 + r;
            #pragma unroll
            for (int t = 0; t < 8; t++)
                C[(size_t)s*HID + n0 + t*16 + l16] = acc[mi][t][r];
        }
}

// ---------------------------------------------------------------- launcher
extern "C" void kernel_launch(void* const* d_in, const int* in_sizes, int n_in,
                              void* d_out, int out_size, void* d_ws, size_t ws_size,
                              hipStream_t stream) {
    const float* hidden = (const float*)d_in[0];
    const float* cosb   = (const float*)d_in[1];
    const float* sinb   = (const float*)d_in[2];
    const float* Wq     = (const float*)d_in[3];
    const float* bq     = (const float*)d_in[4];
    const float* Wk     = (const float*)d_in[5];
    const float* bk     = (const float*)d_in[6];
    const float* Wv     = (const float*)d_in[7];
    const float* bv     = (const float*)d_in[8];
    const float* Wo     = (const float*)d_in[9];
    float* out = (float*)d_out;

    char* ws = (char*)d_ws;
    short* hid_bf  = (short*)(ws);                         // 2048*3584*2  = 14,680,064
    short* wqkv_bf = (short*)(ws + 14680064);              // 4608*3584*2  = 33,030,144
    short* wo_bf   = (short*)(ws + 47710208);              // 3584*3584*2  = 25,690,112
    short* q_bf    = (short*)(ws + 73400320);              // 28*2048*128*2= 14,680,064
    short* k_bf    = (short*)(ws + 88080384);              //  4*2048*128*2=  2,097,152
    short* vt_bf   = (short*)(ws + 90177536);              //  4*128*2048*2=  2,097,152
    short* at_bf   = (short*)(ws + 92274688);              // 2048*3584*2  = 14,680,064

    auto cvt = [&](const float* s, short* d, size_t n){
        int n8 = (int)(n/8);
        cvt_f32_bf16<<<dim3((n8+255)/256), dim3(256), 0, stream>>>(s, d, n8);
    };
    cvt(hidden, hid_bf,  (size_t)SEQ*HID);
    cvt(Wq, wqkv_bf,                      (size_t)3584*HID);
    cvt(Wk, wqkv_bf + (size_t)3584*HID,   (size_t)512*HID);
    cvt(Wv, wqkv_bf + (size_t)4096*HID,   (size_t)512*HID);
    cvt(Wo, wo_bf,                        (size_t)3584*HID);

    gemm_qkv_rope<<<dim3(36,16), dim3(256), 0, stream>>>(hid_bf, wqkv_bf, bq, bk, bv,
                                                         cosb, sinb, q_bf, k_bf, vt_bf);
    attn_kernel<<<dim3(448), dim3(256), 0, stream>>>(q_bf, k_bf, vt_bf, at_bf);
    gemm_out<<<dim3(28,16), dim3(256), 0, stream>>>(at_bf, wo_bf, out);
}

// Round 5
// 540.637 us; speedup vs baseline: 1.7790x; 1.0653x over previous
//
#include <hip/hip_runtime.h>
#include <hip/hip_bf16.h>
#include <cmath>
#include <cstdint>

// Problem constants
#define SEQ    2048
#define HID    3584
#define NH     28
#define NKV    4
#define HD     128
#define NTOT   4608          // 3584 q + 512 k + 512 v
#define KOFF   3584
#define VOFF   4096
#define QSCALE 0.08838834764831845f   // 1/sqrt(128)
#define LOG2E  1.4426950408889634f

typedef __attribute__((ext_vector_type(8))) short bf16x8;
typedef __attribute__((ext_vector_type(4))) float f32x4;

__device__ inline short f2bf(float f){
    union { float f; uint32_t u; } c; c.f = f;
    uint32_t u = c.u;
    uint32_t r = (u + 0x7fffu + ((u >> 16) & 1u)) >> 16;
    return (short)r;
}

// async global->LDS, 16B per lane; LDS dest = wave-uniform base + lane*16
__device__ __forceinline__ void gl_lds16(const short* g, short* l) {
    __builtin_amdgcn_global_load_lds(
        (const __attribute__((address_space(1))) void*)g,
        (__attribute__((address_space(3))) void*)l,
        16, 0, 0);
}

#define WAIT_VM8  asm volatile("s_waitcnt vmcnt(8)" ::: "memory")
#define WAIT_VM0  asm volatile("s_waitcnt vmcnt(0)" ::: "memory")
#define WAIT_LGKM asm volatile("s_waitcnt lgkmcnt(0)" ::: "memory")
#define BARRIER   asm volatile("s_barrier" ::: "memory")

// ---------------------------------------------------------------- convert
__global__ void cvt_f32_bf16(const float* __restrict__ src, short* __restrict__ dst, int n8){
    int i = blockIdx.x * blockDim.x + threadIdx.x;
    if (i >= n8) return;
    float4 a = ((const float4*)src)[2*i];
    float4 b = ((const float4*)src)[2*i+1];
    bf16x8 o;
    o[0]=f2bf(a.x); o[1]=f2bf(a.y); o[2]=f2bf(a.z); o[3]=f2bf(a.w);
    o[4]=f2bf(b.x); o[5]=f2bf(b.y); o[6]=f2bf(b.z); o[7]=f2bf(b.w);
    ((bf16x8*)dst)[i] = o;
}

// ---------------------------------------------------------------- QKV GEMM + bias + RoPE + layout
// Double-buffered m97: global_load_lds width=16 prefetch of tile k+1 while
// computing tile k. Raw s_waitcnt vmcnt(8)/s_barrier (NOT __syncthreads -- its
// forced vmcnt(0) would drain the prefetch). XOR chunk swizzle for bank-free
// b128 fragment reads (verified R4: conflicts 1.03e7 -> 0).
__launch_bounds__(256)
__global__ void gemm_qkv_rope(const short* __restrict__ A, const short* __restrict__ Bw,
                              const float* __restrict__ bq, const float* __restrict__ bk,
                              const float* __restrict__ bv,
                              const float* __restrict__ cosb, const float* __restrict__ sinb,
                              short* __restrict__ qo, short* __restrict__ ko, short* __restrict__ vto)
{
    __shared__ short ldsA[2][128*64];
    __shared__ short ldsB[2][128*64];
    const int tid  = threadIdx.x;
    const int wave = tid >> 6, lane = tid & 63;
    const int lq   = lane >> 4, l16 = lane & 15;
    const int m0   = blockIdx.y * 128, n0 = blockIdx.x * 128;

    const int lrow = lane >> 3;                  // 0..7
    const int gchk = ((lane & 7) ^ lrow) << 3;   // swizzled 16B-chunk offset (shorts)

    const short* Ab = &A [(size_t)(m0 + wave*8 + lrow)*HID + gchk];
    const short* Bb = &Bw[(size_t)(n0 + wave*8 + lrow)*HID + gchk];

    f32x4 acc[2][8];
    #pragma unroll
    for (int i = 0; i < 2; i++)
        #pragma unroll
        for (int j = 0; j < 8; j++) acc[i][j] = (f32x4){0.f,0.f,0.f,0.f};

    auto issue = [&](int k0, int b) {
        #pragma unroll
        for (int j = 0; j < 4; j++) {
            gl_lds16(Ab + (size_t)j*32*HID + k0, &ldsA[b][(j*32 + wave*8)*64]);
            gl_lds16(Bb + (size_t)j*32*HID + k0, &ldsB[b][(j*32 + wave*8)*64]);
        }
    };
    auto compute = [&](int b) {
        #pragma unroll
        for (int ks = 0; ks < 2; ks++) {
            bf16x8 af[2], bfr[8];
            #pragma unroll
            for (int mi = 0; mi < 2; mi++)
                af[mi] = *(bf16x8*)&ldsA[b][(wave*32 + mi*16 + l16)*64 + (((ks*4 + lq) ^ (l16 & 7)) << 3)];
            #pragma unroll
            for (int ti = 0; ti < 8; ti++)
                bfr[ti] = *(bf16x8*)&ldsB[b][(ti*16 + l16)*64 + (((ks*4 + lq) ^ (l16 & 7)) << 3)];
            #pragma unroll
            for (int mi = 0; mi < 2; mi++)
                #pragma unroll
                for (int ti = 0; ti < 8; ti++)
                    acc[mi][ti] = __builtin_amdgcn_mfma_f32_16x16x32_bf16(af[mi], bfr[ti], acc[mi][ti], 0,0,0);
        }
    };

    // 56 K-tiles. Prologue: tile 0 -> buf0. Pairs (1,2)..(53,54), tail 55.
    issue(0, 0);
    for (int t = 1; t < 54; t += 2) {
        issue(t*64, 1);
        WAIT_VM8; BARRIER;
        compute(0);
        WAIT_LGKM; BARRIER;
        issue((t+1)*64, 0);
        WAIT_VM8; BARRIER;
        compute(1);
        WAIT_LGKM; BARRIER;
    }
    issue(55*64, 1);
    WAIT_VM8; BARRIER;
    compute(0);                       // tile 54
    WAIT_VM0; BARRIER;
    compute(1);                       // tile 55

    if (n0 < KOFF) {               // Q region
        int h = n0 >> 7;
        #pragma unroll
        for (int mi = 0; mi < 2; mi++)
            #pragma unroll
            for (int r = 0; r < 4; r++) {
                int s = m0 + wave*32 + mi*16 + lq*4 + r;
                size_t base = ((size_t)h*SEQ + s)*HD;
                #pragma unroll
                for (int t = 0; t < 4; t++) {
                    int d = t*16 + l16;
                    float c  = cosb[s*HD + d];
                    float sn = sinb[s*HD + d];
                    float x0 = acc[mi][t  ][r] + bq[n0 + t*16 + l16];
                    float x1 = acc[mi][t+4][r] + bq[n0 + 64 + t*16 + l16];
                    qo[base + d]      = f2bf((x0*c - x1*sn) * QSCALE);
                    qo[base + d + 64] = f2bf((x1*c + x0*sn) * QSCALE);
                }
            }
    } else if (n0 < VOFF) {        // K region
        int h = (n0 - KOFF) >> 7;
        #pragma unroll
        for (int mi = 0; mi < 2; mi++)
            #pragma unroll
            for (int r = 0; r < 4; r++) {
                int s = m0 + wave*32 + mi*16 + lq*4 + r;
                size_t base = ((size_t)h*SEQ + s)*HD;
                #pragma unroll
                for (int t = 0; t < 4; t++) {
                    int d = t*16 + l16;
                    float c  = cosb[s*HD + d];
                    float sn = sinb[s*HD + d];
                    float x0 = acc[mi][t  ][r] + bk[n0 - KOFF + t*16 + l16];
                    float x1 = acc[mi][t+4][r] + bk[n0 - KOFF + 64 + t*16 + l16];
                    ko[base + d]      = f2bf(x0*c - x1*sn);
                    ko[base + d + 64] = f2bf(x1*c + x0*sn);
                }
            }
    } else {                       // V region -> transposed store vt[h][d][s]
        int h = (n0 - VOFF) >> 7;
        #pragma unroll
        for (int mi = 0; mi < 2; mi++)
            #pragma unroll
            for (int r = 0; r < 4; r++) {
                int s = m0 + wave*32 + mi*16 + lq*4 + r;
                #pragma unroll
                for (int t = 0; t < 8; t++) {
                    int d = t*16 + l16;
                    float v = acc[mi][t][r] + bv[n0 - VOFF + t*16 + l16];
                    vto[((size_t)h*HD + d)*SEQ + s] = f2bf(v);
                }
            }
    }
}

// ---------------------------------------------------------------- flash attention v3 (unchanged, verified R3/R4)
#define KP 136
#define VP 72
__launch_bounds__(256)
__global__ void attn_kernel(const short* __restrict__ q, const short* __restrict__ k,
                            const short* __restrict__ vt, short* __restrict__ out)
{
    const int b  = blockIdx.x;
    const int h  = b % NH;
    const int qt = 15 - (b / NH);          // heavy q-tiles dispatched first
    const int q0b = qt * 128;
    const int hkv = h / 7;

    const int tid = threadIdx.x;
    const int wave = tid >> 6, lane = tid & 63;
    const int lq = lane >> 4, l16 = lane & 15;

    const short* Q  = q  + (size_t)h   * SEQ * HD;
    const short* Kp = k  + (size_t)hkv * SEQ * HD;
    const short* VT = vt + (size_t)hkv * HD * SEQ;

    __shared__ short kbuf[64*KP];
    __shared__ short vbuf[128*VP];
    __shared__ short pbuf[4][2][16*VP];

    const int qr[2] = { q0b + wave*16, q0b + 64 + wave*16 };

    bf16x8 qf[2][4];
    #pragma unroll
    for (int m = 0; m < 2; m++)
        #pragma unroll
        for (int ks = 0; ks < 4; ks++)
            qf[m][ks] = *(const bf16x8*)&Q[(size_t)(qr[m] + l16)*HD + ks*32 + lq*8];

    f32x4 o[2][8];
    #pragma unroll
    for (int m = 0; m < 2; m++)
        #pragma unroll
        for (int t = 0; t < 8; t++) o[m][t] = (f32x4){0.f,0.f,0.f,0.f};
    float m_[2][4] = {{-INFINITY,-INFINITY,-INFINITY,-INFINITY},
                      {-INFINITY,-INFINITY,-INFINITY,-INFINITY}};
    float l_[2][4] = {{0.f,0.f,0.f,0.f},{0.f,0.f,0.f,0.f}};

    const int nchunk = (q0b >> 6) + 2;
    for (int ci = 0; ci < nchunk; ci++) {
        const int k0 = ci << 6;
        __syncthreads();
        #pragma unroll
        for (int i = 0; i < 4; i++) {
            int c = tid + i*256;             // 1024 chunks of 8 shorts
            int row = c >> 4, pos = c & 15;
            *(bf16x8*)&kbuf[row*KP + pos*8] =
                *(const bf16x8*)&Kp[(size_t)(k0 + row)*HD + pos*8];
        }
        #pragma unroll
        for (int i = 0; i < 4; i++) {
            int c = tid + i*256;
            int d = c >> 3, pos = c & 7;
            *(bf16x8*)&vbuf[d*VP + pos*8] =
                *(const bf16x8*)&VT[(size_t)d*SEQ + k0 + pos*8];
        }
        __syncthreads();

        f32x4 sc[2][4];
        #pragma unroll
        for (int m = 0; m < 2; m++)
            #pragma unroll
            for (int nt = 0; nt < 4; nt++) sc[m][nt] = (f32x4){0.f,0.f,0.f,0.f};
        #pragma unroll
        for (int nt = 0; nt < 4; nt++)
            #pragma unroll
            for (int ks = 0; ks < 4; ks++) {
                bf16x8 kf = *(bf16x8*)&kbuf[(nt*16 + l16)*KP + ks*32 + lq*8];
                sc[0][nt] = __builtin_amdgcn_mfma_f32_16x16x32_bf16(qf[0][ks], kf, sc[0][nt], 0,0,0);
                sc[1][nt] = __builtin_amdgcn_mfma_f32_16x16x32_bf16(qf[1][ks], kf, sc[1][nt], 0,0,0);
            }

        #pragma unroll
        for (int m = 0; m < 2; m++) {
            #pragma unroll
            for (int nt = 0; nt < 4; nt++) {
                int col = k0 + nt*16 + l16;
                #pragma unroll
                for (int r = 0; r < 4; r++) {
                    int row = qr[m] + lq*4 + r;
                    if (col > row) sc[m][nt][r] = -INFINITY;
                }
            }
            float alpha[4];
            #pragma unroll
            for (int r = 0; r < 4; r++) {
                float mx = fmaxf(fmaxf(sc[m][0][r], sc[m][1][r]),
                                 fmaxf(sc[m][2][r], sc[m][3][r]));
                #pragma unroll
                for (int sft = 8; sft >= 1; sft >>= 1) mx = fmaxf(mx, __shfl_xor(mx, sft));
                float nm = fmaxf(m_[m][r], mx);
                alpha[r] = exp2f((m_[m][r] - nm) * LOG2E);
                m_[m][r] = nm;
                float sm = 0.f;
                #pragma unroll
                for (int nt = 0; nt < 4; nt++) {
                    float p = exp2f((sc[m][nt][r] - nm) * LOG2E);
                    sc[m][nt][r] = p;
                    sm += p;
                }
                #pragma unroll
                for (int sft = 8; sft >= 1; sft >>= 1) sm += __shfl_xor(sm, sft);
                l_[m][r] = l_[m][r]*alpha[r] + sm;
            }
            #pragma unroll
            for (int t = 0; t < 8; t++)
                #pragma unroll
                for (int r = 0; r < 4; r++) o[m][t][r] *= alpha[r];
            #pragma unroll
            for (int r = 0; r < 4; r++)
                #pragma unroll
                for (int nt = 0; nt < 4; nt++)
                    pbuf[wave][m][(lq*4 + r)*VP + nt*16 + l16] = f2bf(sc[m][nt][r]);
        }
        __syncthreads();

        bf16x8 pf[2][2];
        #pragma unroll
        for (int m = 0; m < 2; m++)
            #pragma unroll
            for (int kk = 0; kk < 2; kk++)
                pf[m][kk] = *(bf16x8*)&pbuf[wave][m][l16*VP + kk*32 + lq*8];

        #pragma unroll
        for (int t = 0; t < 8; t++)
            #pragma unroll
            for (int kk = 0; kk < 2; kk++) {
                bf16x8 vf = *(bf16x8*)&vbuf[(t*16 + l16)*VP + kk*32 + lq*8];
                o[0][t] = __builtin_amdgcn_mfma_f32_16x16x32_bf16(pf[0][kk], vf, o[0][t], 0,0,0);
                o[1][t] = __builtin_amdgcn_mfma_f32_16x16x32_bf16(pf[1][kk], vf, o[1][t], 0,0,0);
            }
    }

    #pragma unroll
    for (int m = 0; m < 2; m++)
        #pragma unroll
        for (int r = 0; r < 4; r++) {
            float inv = 1.0f / l_[m][r];
            int s = qr[m] + lq*4 + r;
            #pragma unroll
            for (int t = 0; t < 8; t++)
                out[(size_t)s*HID + h*HD + t*16 + l16] = f2bf(o[m][t][r]*inv);
        }
}

// ---------------------------------------------------------------- output GEMM (fp32 out, no bias), dbuf
__launch_bounds__(256)
__global__ void gemm_out(const short* __restrict__ A, const short* __restrict__ Bw,
                         float* __restrict__ C)
{
    __shared__ short ldsA[2][128*64];
    __shared__ short ldsB[2][128*64];
    const int tid  = threadIdx.x;
    const int wave = tid >> 6, lane = tid & 63;
    const int lq   = lane >> 4, l16 = lane & 15;
    const int m0   = blockIdx.y * 128, n0 = blockIdx.x * 128;

    const int lrow = lane >> 3;
    const int gchk = ((lane & 7) ^ lrow) << 3;

    const short* Ab = &A [(size_t)(m0 + wave*8 + lrow)*HID + gchk];
    const short* Bb = &Bw[(size_t)(n0 + wave*8 + lrow)*HID + gchk];

    f32x4 acc[2][8];
    #pragma unroll
    for (int i = 0; i < 2; i++)
        #pragma unroll
        for (int j = 0; j < 8; j++) acc[i][j] = (f32x4){0.f,0.f,0.f,0.f};

    auto issue = [&](int k0, int b) {
        #pragma unroll
        for (int j = 0; j < 4; j++) {
            gl_lds16(Ab + (size_t)j*32*HID + k0, &ldsA[b][(j*32 + wave*8)*64]);
            gl_lds16(Bb + (size_t)j*32*HID + k0, &ldsB[b][(j*32 + wave*8)*64]);
        }
    };
    auto compute = [&](int b) {
        #pragma unroll
        for (int ks = 0; ks < 2; ks++) {
            bf16x8 af[2], bfr[8];
            #pragma unroll
            for (int mi = 0; mi < 2; mi++)
                af[mi] = *(bf16x8*)&ldsA[b][(wave*32 + mi*16 + l16)*64 + (((ks*4 + lq) ^ (l16 & 7)) << 3)];
            #pragma unroll
            for (int ti = 0; ti < 8; ti++)
                bfr[ti] = *(bf16x8*)&ldsB[b][(ti*16 + l16)*64 + (((ks*4 + lq) ^ (l16 & 7)) << 3)];
            #pragma unroll
            for (int mi = 0; mi < 2; mi++)
                #pragma unroll
                for (int ti = 0; ti < 8; ti++)
                    acc[mi][ti] = __builtin_amdgcn_mfma_f32_16x16x32_bf16(af[mi], bfr[ti], acc[mi][ti], 0,0,0);
        }
    };

    issue(0, 0);
    for (int t = 1; t < 54; t += 2) {
        issue(t*64, 1);
        WAIT_VM8; BARRIER;
        compute(0);
        WAIT_LGKM; BARRIER;
        issue((t+1)*64, 0);
        WAIT_VM8; BARRIER;
        compute(1);
        WAIT_LGKM; BARRIER;
    }
    issue(55*64, 1);
    WAIT_VM8; BARRIER;
    compute(0);                       // tile 54
    WAIT_VM0; BARRIER;
    compute(1);                       // tile 55

    #pragma unroll
    for (int mi = 0; mi < 2; mi++)
        #pragma unroll
        for (int r = 0; r < 4; r++) {
            int s = m0 + wave*32 + mi*16 + lq*4 + r;
            #pragma unroll
            for (int t = 0; t < 8; t++)
                C[(size_t)s*HID + n0 + t*16 + l16] = acc[mi][t][r];
        }
}

// ---------------------------------------------------------------- launcher
extern "C" void kernel_launch(void* const* d_in, const int* in_sizes, int n_in,
                              void* d_out, int out_size, void* d_ws, size_t ws_size,
                              hipStream_t stream) {
    const float* hidden = (const float*)d_in[0];
    const float* cosb   = (const float*)d_in[1];
    const float* sinb   = (const float*)d_in[2];
    const float* Wq     = (const float*)d_in[3];
    const float* bq     = (const float*)d_in[4];
    const float* Wk     = (const float*)d_in[5];
    const float* bk     = (const float*)d_in[6];
    const float* Wv     = (const float*)d_in[7];
    const float* bv     = (const float*)d_in[8];
    const float* Wo     = (const float*)d_in[9];
    float* out = (float*)d_out;

    char* ws = (char*)d_ws;
    short* hid_bf  = (short*)(ws);                         // 2048*3584*2  = 14,680,064
    short* wqkv_bf = (short*)(ws + 14680064);              // 4608*3584*2  = 33,030,144
    short* wo_bf   = (short*)(ws + 47710208);              // 3584*3584*2  = 25,690,112
    short* q_bf    = (short*)(ws + 73400320);              // 28*2048*128*2= 14,680,064
    short* k_bf    = (short*)(ws + 88080384);              //  4*2048*128*2=  2,097,152
    short* vt_bf   = (short*)(ws + 90177536);              //  4*128*2048*2=  2,097,152
    short* at_bf   = (short*)(ws + 92274688);              // 2048*3584*2  = 14,680,064

    auto cvt = [&](const float* s, short* d, size_t n){
        int n8 = (int)(n/8);
        cvt_f32_bf16<<<dim3((n8+255)/256), dim3(256), 0, stream>>>(s, d, n8);
    };
    cvt(hidden, hid_bf,  (size_t)SEQ*HID);
    cvt(Wq, wqkv_bf,                      (size_t)3584*HID);
    cvt(Wk, wqkv_bf + (size_t)3584*HID,   (size_t)512*HID);
    cvt(Wv, wqkv_bf + (size_t)4096*HID,   (size_t)512*HID);
    cvt(Wo, wo_bf,                        (size_t)3584*HID);

    gemm_qkv_rope<<<dim3(36,16), dim3(256), 0, stream>>>(hid_bf, wqkv_bf, bq, bk, bv,
                                                         cosb, sinb, q_bf, k_bf, vt_bf);
    attn_kernel<<<dim3(448), dim3(256), 0, stream>>>(q_bf, k_bf, vt_bf, at_bf);
    gemm_out<<<dim3(28,16), dim3(256), 0, stream>>>(at_bf, wo_bf, out);
}